// Round 9
// baseline (507.897 us; speedup 1.0000x reference)
//
#include <hip/hip_runtime.h>
#include <hip/hip_bf16.h>
#include <cstdint>
#include <cstddef>

#define BS 16
#define SEQ 3900
#define DIM 512
#define NHEAD 8
#define DH 64
#define CHUNK 200
#define NB 20
#define NR 100
#define NP 4000
#define MAXPOS 512
#define MD 62400              // dense rows = BS*SEQ

typedef __attribute__((ext_vector_type(8))) short bf16x8;
typedef __attribute__((ext_vector_type(8))) unsigned short u16x8;
typedef __attribute__((ext_vector_type(4))) float f32x4;
#define MFMA_BF16 __builtin_amdgcn_mfma_f32_16x16x32_bf16

// bf16 helpers
static __device__ __forceinline__ float bf2f(unsigned short u) {
  union { unsigned int i; float f; } v; v.i = ((unsigned int)u) << 16; return v.f;
}
static __device__ __forceinline__ unsigned short f2bf(float f) {   // RNE
  unsigned int x = __float_as_uint(f);
  unsigned int lsb = (x >> 16) & 1u;
  x += 0x7fffu + lsb;
  return (unsigned short)(x >> 16);
}
// packed pair f32 -> 2x bf16 in one u32 (low = lo).  Header intrinsic, RNE.
static __device__ __forceinline__ unsigned int pkbf(float lo, float hi) {
  union { __hip_bfloat162 h2; unsigned int u; } c;
  c.h2 = __float22bfloat162_rn(make_float2(lo, hi));
  return c.u;
}

// global -> LDS direct copy, 16B per lane
static __device__ __forceinline__ void gload16(const void* g, void* l) {
  auto gp = reinterpret_cast<const __attribute__((address_space(1))) unsigned int*>(
      reinterpret_cast<uintptr_t>(g));
  auto lp = reinterpret_cast<__attribute__((address_space(3))) unsigned int*>(
      reinterpret_cast<uintptr_t>(l));
  __builtin_amdgcn_global_load_lds(gp, lp, 16, 0, 0);
}

// Pad-chunk addressing: row n of a [n][512] bf16 matrix stored in the pad rows
// (t=3900..3999) of a [16][4000][512] workspace buffer.  100 rows per chunk.
static __device__ __forceinline__ const unsigned short* wt_row(
    const unsigned short* base, int n) {
  unsigned ch = (unsigned)n / 100u;
  unsigned rr = (unsigned)n - ch * 100u;
  return base + (size_t)ch * (NP * DIM) + (size_t)SEQ * DIM + (size_t)rr * DIM;
}

// ---------------------------------------------------------------------------
// Kernel 0a: cast rel-pos table window (rows 305..720) to bf16 -> Kb pads(b0).
// ---------------------------------------------------------------------------
__global__ __launch_bounds__(256) void prep_table(
    const float* __restrict__ table, unsigned short* __restrict__ Tb)
{
  int idx = (blockIdx.x * 256 + threadIdx.x) * 4;
  if (idx < 416 * 64) {
    float4 f = *reinterpret_cast<const float4*>(table + (size_t)305 * 64 + idx);
    ushort4 o;
    o.x = f2bf(f.x); o.y = f2bf(f.y); o.z = f2bf(f.z); o.w = f2bf(f.w);
    *reinterpret_cast<ushort4*>(Tb + idx) = o;
  }
}

// ---------------------------------------------------------------------------
// Kernel 0b: transpose+cast W[k][n] fp32 -> scale*Wt[n][k] bf16 into pad rows.
// wq gets scale = 0.125*log2(e): attention then uses exp2 directly (and Qtab,
// computed from the pre-scaled Q, inherits the scale).
// ---------------------------------------------------------------------------
__global__ __launch_bounds__(256) void wtrans(
    const float* __restrict__ W, int ldn, int n_off, float scale,
    unsigned short* __restrict__ base)
{
  __shared__ float ts[64][65];
  const int tid = threadIdx.x;
  const int n0 = blockIdx.x * 64;
  const int k0 = blockIdx.y * 64;
  {
    int kl = tid >> 4;
    int nl = (tid & 15) * 4;
#pragma unroll
    for (int p = 0; p < 4; ++p) {
      float4 f = *reinterpret_cast<const float4*>(
          W + (size_t)(k0 + kl + p * 16) * ldn + n0 + nl);
      ts[kl + p * 16][nl + 0] = f.x;
      ts[kl + p * 16][nl + 1] = f.y;
      ts[kl + p * 16][nl + 2] = f.z;
      ts[kl + p * 16][nl + 3] = f.w;
    }
  }
  __syncthreads();
  {
    int nl = tid >> 2;
    int kof = (tid & 3) * 16;
    int n = n0 + nl + n_off;
    unsigned ch = (unsigned)n / 100u;
    unsigned rr = (unsigned)n - ch * 100u;
    unsigned short* dst = base + (size_t)ch * (NP * DIM) + (size_t)SEQ * DIM
                          + (size_t)rr * DIM + k0 + kof;
    u16x8 o0, o1;
#pragma unroll
    for (int i = 0; i < 8; ++i) o0[i] = f2bf(ts[kof + i][nl] * scale);
#pragma unroll
    for (int i = 0; i < 8; ++i) o1[i] = f2bf(ts[kof + 8 + i][nl] * scale);
    *reinterpret_cast<u16x8*>(dst) = o0;
    *reinterpret_cast<u16x8*>(dst + 8) = o1;
  }
}

// ---------------------------------------------------------------------------
// Kernel 0c: cast x fp32 -> dense bf16 xb (stored in d_out scratch).
// ---------------------------------------------------------------------------
__global__ __launch_bounds__(256) void cast_x(
    const float* __restrict__ x, unsigned short* __restrict__ xb)
{
  const size_t total = (size_t)MD * DIM;
  size_t i = ((size_t)blockIdx.x * 256 + threadIdx.x) * 8;
  const size_t stride = (size_t)gridDim.x * 256 * 8;
  for (; i < total; i += stride) {
    float4 f0 = *reinterpret_cast<const float4*>(x + i);
    float4 f1 = *reinterpret_cast<const float4*>(x + i + 4);
    u16x8 o;
    o[0] = f2bf(f0.x); o[1] = f2bf(f0.y); o[2] = f2bf(f0.z); o[3] = f2bf(f0.w);
    o[4] = f2bf(f1.x); o[5] = f2bf(f1.y); o[6] = f2bf(f1.z); o[7] = f2bf(f1.w);
    *reinterpret_cast<u16x8*>(xb + i) = o;
  }
}

// ---------------------------------------------------------------------------
// Kernel 1: QKV projection, pure-bf16 MFMA with global_load_lds staging.
// ---------------------------------------------------------------------------
__global__ __launch_bounds__(256) void gemm_qkv(
    const unsigned short* __restrict__ xb, const unsigned short* __restrict__ WtBase,
    unsigned short* __restrict__ Qb, unsigned short* __restrict__ Kb,
    unsigned short* __restrict__ Vb)
{
  __shared__ unsigned short As[2][8 * 512];
  __shared__ unsigned short Bs[2][8 * 512];

  int bid = blockIdx.x;                       // 5856 = 8 * 732
  bid = (bid & 7) * 732 + (bid >> 3);
  const int bm = bid / 12, bn = bid % 12;
  const int m0 = bm * 128, n0 = bn * 128;
  const int tid = threadIdx.x;
  const int wv = tid >> 6, ln = tid & 63;
  const int wr = wv >> 1, wc = wv & 1;
  const int lr = ln & 15, lg = ln >> 4;

  const int sl = ln & 15, sk = (ln >> 4) * 8;
  const int q0 = wv * 2, q1 = q0 + 1;
  int ar0 = m0 + (q0 >> 2) * 64 + (q0 & 3) * 16 + sl; if (ar0 >= MD) ar0 = MD - 1;
  int ar1 = m0 + (q1 >> 2) * 64 + (q1 & 3) * 16 + sl; if (ar1 >= MD) ar1 = MD - 1;
  const unsigned short* aS0 = xb + (size_t)ar0 * DIM + sk;
  const unsigned short* aS1 = xb + (size_t)ar1 * DIM + sk;
  const unsigned short* bS0 = wt_row(WtBase, n0 + (q0 >> 2) * 64 + (q0 & 3) * 16 + sl) + sk;
  const unsigned short* bS1 = wt_row(WtBase, n0 + (q1 >> 2) * 64 + (q1 & 3) * 16 + sl) + sk;

  f32x4 acc[4][4];
#pragma unroll
  for (int i = 0; i < 4; ++i)
#pragma unroll
    for (int j = 0; j < 4; ++j) acc[i][j] = (f32x4){0.f, 0.f, 0.f, 0.f};

#define STG_QKV(buf, koff)                          \
  gload16(aS0 + (koff), &As[buf][q0 * 512]);        \
  gload16(aS1 + (koff), &As[buf][q1 * 512]);        \
  gload16(bS0 + (koff), &Bs[buf][q0 * 512]);        \
  gload16(bS1 + (koff), &Bs[buf][q1 * 512]);

  STG_QKV(0, 0)
  __syncthreads();

  int p = 0;
  for (int s = 0; s < 16; ++s) {
    if (s < 15) { STG_QKV(p ^ 1, (s + 1) * 32) }
    const unsigned short* asp = As[p];
    const unsigned short* bsp = Bs[p];
    bf16x8 af[4], bfr[4];
#pragma unroll
    for (int mt = 0; mt < 4; ++mt)
      af[mt] = *reinterpret_cast<const bf16x8*>(asp + (wr * 4 + mt) * 512 + ln * 8);
#pragma unroll
    for (int nt = 0; nt < 4; ++nt)
      bfr[nt] = *reinterpret_cast<const bf16x8*>(bsp + (wc * 4 + nt) * 512 + ln * 8);
#pragma unroll
    for (int mt = 0; mt < 4; ++mt)
#pragma unroll
      for (int nt = 0; nt < 4; ++nt)
        acc[mt][nt] = MFMA_BF16(af[mt], bfr[nt], acc[mt][nt], 0, 0, 0);
    __syncthreads();
    p ^= 1;
  }

  unsigned short* dst; int nbase;
  if (n0 < 512)       { dst = Qb; nbase = 0; }
  else if (n0 < 1024) { dst = Kb; nbase = 512; }
  else                { dst = Vb; nbase = 1024; }
  const int colg0 = n0 + wc * 64 - nbase;
#pragma unroll
  for (int mt = 0; mt < 4; ++mt) {
#pragma unroll
    for (int e = 0; e < 4; ++e) {
      unsigned rd = m0 + wr * 64 + mt * 16 + lg * 4 + e;
      if (rd < MD) {
        unsigned bb = rd / 3900u;
        unsigned tt = rd - bb * 3900u;
        size_t rowoff = ((size_t)bb * NP + tt) * DIM;
#pragma unroll
        for (int nt = 0; nt < 4; ++nt)
          dst[rowoff + colg0 + nt * 16 + lr] = f2bf(acc[mt][nt][e]);
      }
    }
  }
}

// ---------------------------------------------------------------------------
// Kernel 3: output projection, same structure; fp32 output + bias.
// ---------------------------------------------------------------------------
__global__ __launch_bounds__(256) void gemm_out(
    const unsigned short* __restrict__ Ob, const unsigned short* __restrict__ WoBase,
    const float* __restrict__ bias, float* __restrict__ out)
{
  __shared__ unsigned short As[2][8 * 512];
  __shared__ unsigned short Bs[2][8 * 512];

  int bid = blockIdx.x;                       // 1952 = 8 * 244
  bid = (bid & 7) * 244 + (bid >> 3);
  const int bm = bid / 4, bn = bid % 4;
  const int m0 = bm * 128, n0 = bn * 128;
  const int tid = threadIdx.x;
  const int wv = tid >> 6, ln = tid & 63;
  const int wr = wv >> 1, wc = wv & 1;
  const int lr = ln & 15, lg = ln >> 4;

  const int sl = ln & 15, sk = (ln >> 4) * 8;
  const int q0 = wv * 2, q1 = q0 + 1;
  unsigned ar0 = m0 + (q0 >> 2) * 64 + (q0 & 3) * 16 + sl; if (ar0 >= MD) ar0 = MD - 1;
  unsigned ar1 = m0 + (q1 >> 2) * 64 + (q1 & 3) * 16 + sl; if (ar1 >= MD) ar1 = MD - 1;
  unsigned b0b = ar0 / 3900u, t0 = ar0 - b0b * 3900u;
  unsigned b1b = ar1 / 3900u, t1 = ar1 - b1b * 3900u;
  const unsigned short* aS0 = Ob + ((size_t)b0b * NP + t0) * DIM + sk;
  const unsigned short* aS1 = Ob + ((size_t)b1b * NP + t1) * DIM + sk;
  const unsigned short* bS0 = wt_row(WoBase, n0 + (q0 >> 2) * 64 + (q0 & 3) * 16 + sl) + sk;
  const unsigned short* bS1 = wt_row(WoBase, n0 + (q1 >> 2) * 64 + (q1 & 3) * 16 + sl) + sk;

  f32x4 acc[4][4];
#pragma unroll
  for (int i = 0; i < 4; ++i)
#pragma unroll
    for (int j = 0; j < 4; ++j) acc[i][j] = (f32x4){0.f, 0.f, 0.f, 0.f};

#define STG_OUT(buf, koff)                          \
  gload16(aS0 + (koff), &As[buf][q0 * 512]);        \
  gload16(aS1 + (koff), &As[buf][q1 * 512]);        \
  gload16(bS0 + (koff), &Bs[buf][q0 * 512]);        \
  gload16(bS1 + (koff), &Bs[buf][q1 * 512]);

  STG_OUT(0, 0)
  __syncthreads();

  int p = 0;
  for (int s = 0; s < 16; ++s) {
    if (s < 15) { STG_OUT(p ^ 1, (s + 1) * 32) }
    const unsigned short* asp = As[p];
    const unsigned short* bsp = Bs[p];
    bf16x8 af[4], bfr[4];
#pragma unroll
    for (int mt = 0; mt < 4; ++mt)
      af[mt] = *reinterpret_cast<const bf16x8*>(asp + (wr * 4 + mt) * 512 + ln * 8);
#pragma unroll
    for (int nt = 0; nt < 4; ++nt)
      bfr[nt] = *reinterpret_cast<const bf16x8*>(bsp + (wc * 4 + nt) * 512 + ln * 8);
#pragma unroll
    for (int mt = 0; mt < 4; ++mt)
#pragma unroll
      for (int nt = 0; nt < 4; ++nt)
        acc[mt][nt] = MFMA_BF16(af[mt], bfr[nt], acc[mt][nt], 0, 0, 0);
    __syncthreads();
    p ^= 1;
  }

  float bv[4];
#pragma unroll
  for (int nt = 0; nt < 4; ++nt) bv[nt] = bias[n0 + wc * 64 + nt * 16 + lr];
#pragma unroll
  for (int mt = 0; mt < 4; ++mt) {
#pragma unroll
    for (int e = 0; e < 4; ++e) {
      unsigned rd = m0 + wr * 64 + mt * 16 + lg * 4 + e;
      if (rd < MD) {
#pragma unroll
        for (int nt = 0; nt < 4; ++nt)
          out[(size_t)rd * DIM + n0 + wc * 64 + nt * 16 + lr] = acc[mt][nt][e] + bv[nt];
      }
    }
  }
}

// ---------------------------------------------------------------------------
// Kernel 2: MFMA attention, SWAPPED QK^T (S^T = mfma(K,Q)): lane owns q-row lr,
// keys j = nt*16 + lg*4 + e.
//   * pos gather: one per-lane base + 52 immediate-offset ds_read_u16
//     (index lr*228 + lr - j + 207)
//   * row-sum: in-lane accumulate + shfl_xor(16,32); rcp; 4 shfl redistribute
//   * P -> LDS via 26 paired ds_write_b32 at pq[lr*228 + j] (row-major P),
//     then PV reads the round-7 A-frag path (pq[lr*228 + ks*32 + lg*8]).
// (Round-8's register repack was wrong: one shfl cannot deliver two different
//  elements from one source lane to two destinations -- LDS round-trip kept.)
// LDS layout, staging, Vt reads, C-store identical to proven round-7 kernel.
// ---------------------------------------------------------------------------
#define KS_U16 12800
#define VT_U16 13568
#define PQ_STR 228
#define PQ_U16 (16*PQ_STR)
#define ATTN_LDS_B ((KS_U16 + VT_U16 + 4*PQ_U16) * 2)   // 81920

__global__ __launch_bounds__(256) void attn_mfma(
    const unsigned short* __restrict__ Qb, const unsigned short* __restrict__ Kb,
    const unsigned short* __restrict__ Vb, const unsigned short* __restrict__ Tb,
    unsigned short* __restrict__ Ob)
{
  extern __shared__ unsigned short smem[];
  unsigned short* Ks = smem;
  unsigned short* Vt = smem + KS_U16;

  const int tid = threadIdx.x;
  const int bid = blockIdx.x;
  const int h  = bid & 7;
  const int bm = bid >> 3;
  const int m  = bm % NB;
  const int b  = bm / NB;
  const size_t rowbase = (size_t)b * NP + (size_t)m * CHUNK;
  const int lim = (m == NB - 1) ? NR : CHUNK;

  for (int c = tid; c < CHUNK * 8; c += 256) {
    int j = c >> 3, k0 = (c & 7) * 8;
    uint4 kv = *reinterpret_cast<const uint4*>(Kb + (rowbase + j) * DIM + h * DH + k0);
    int byte = (j * 128 + k0 * 2) ^ ((j & 7) << 4);
    *reinterpret_cast<uint4*>(reinterpret_cast<char*>(Ks) + byte) = kv;
    uint4 vv4 = *reinterpret_cast<const uint4*>(Vb + (rowbase + j) * DIM + h * DH + k0);
    const unsigned short* vs = reinterpret_cast<const unsigned short*>(&vv4);
#pragma unroll
    for (int e = 0; e < 8; ++e)
      Vt[(k0 + e) * 212 + j] = vs[e];
  }
  __syncthreads();

  const int wv = tid >> 6, ln = tid & 63;
  const int lr = ln & 15, lg = ln >> 4;
  unsigned short* pq = smem + KS_U16 + VT_U16 + wv * PQ_U16;
  // gather base: index(lr,j) = lr*(PQ_STR+1) + 207 - j; shifted so imm >= 0
  const unsigned short* pqg = pq + lr * (PQ_STR + 1) + 12 - lg * 4;

  const int nMt = (lim + 15) >> 4;
  for (int mt = wv; mt < nMt; mt += 4) {
    const int i0 = mt << 4;

    const unsigned short* qp = Qb + (rowbase + i0 + lr) * DIM + h * DH + lg * 8;
    bf16x8 qa0 = *reinterpret_cast<const bf16x8*>(qp);
    bf16x8 qa1 = *reinterpret_cast<const bf16x8*>(qp + 32);

    // ---- Qtab = Qs @ T^T (row-major [16][228]; paired converts) ----
#pragma unroll
    for (int ct = 0; ct < 14; ++ct) {
      const unsigned short* tp = Tb + (size_t)(i0 + ct * 16 + lr) * 64 + lg * 8;
      bf16x8 tb0 = *reinterpret_cast<const bf16x8*>(tp);
      bf16x8 tb1 = *reinterpret_cast<const bf16x8*>(tp + 32);
      f32x4 acc = {0.f, 0.f, 0.f, 0.f};
      acc = MFMA_BF16(qa0, tb0, acc, 0, 0, 0);
      acc = MFMA_BF16(qa1, tb1, acc, 0, 0, 0);
      unsigned int u01 = pkbf(acc[0], acc[1]);
      unsigned int u23 = pkbf(acc[2], acc[3]);
      int col = ct * 16 + lr;
      pq[(lg * 4 + 0) * PQ_STR + col] = (unsigned short)u01;
      pq[(lg * 4 + 1) * PQ_STR + col] = (unsigned short)(u01 >> 16);
      pq[(lg * 4 + 2) * PQ_STR + col] = (unsigned short)u23;
      pq[(lg * 4 + 3) * PQ_STR + col] = (unsigned short)(u23 >> 16);
    }

    // ---- QK^T SWAPPED: lane holds S[q-row lr][j = nt*16+lg*4+e] ----
    f32x4 s[13];
#pragma unroll
    for (int nt = 0; nt < 13; ++nt) {
      int row = nt * 16 + lr;
      int b0 = (row * 128 + lg * 16) ^ ((row & 7) << 4);
      int b1 = (row * 128 + 64 + lg * 16) ^ ((row & 7) << 4);
      bf16x8 k0 = *reinterpret_cast<const bf16x8*>(reinterpret_cast<char*>(Ks) + b0);
      bf16x8 k1 = *reinterpret_cast<const bf16x8*>(reinterpret_cast<char*>(Ks) + b1);
      f32x4 acc = {0.f, 0.f, 0.f, 0.f};
      acc = MFMA_BF16(k0, qa0, acc, 0, 0, 0);
      acc = MFMA_BF16(k1, qa1, acc, 0, 0, 0);
      s[nt] = acc;
    }

    // ---- gather (immediate offsets) + exp2 + in-lane sum ----
    float sv = 0.f;
#pragma unroll
    for (int nt = 0; nt < 13; ++nt) {
      const int jb = nt * 16;
#pragma unroll
      for (int e = 0; e < 4; ++e) {
        float pos = bf2f(pqg[195 - jb - e]);
        float t = s[nt][e] + pos;
        float p = (jb + lg * 4 + e < lim) ? exp2f(t) : 0.f;
        s[nt][e] = p;
        sv += p;
      }
    }
    sv += __shfl_xor(sv, 16);
    sv += __shfl_xor(sv, 32);
    float rsv = __builtin_amdgcn_rcpf(sv);
    float rs[4];
#pragma unroll
    for (int e = 0; e < 4; ++e) rs[e] = __shfl(rsv, lg * 4 + e);

    // ---- P -> LDS: row lr, cols 16nt+4lg..+3 (26 paired b32 stores) ----
#pragma unroll
    for (int nt = 0; nt < 13; ++nt) {
      unsigned int w0 = pkbf(s[nt][0], s[nt][1]);
      unsigned int w1 = pkbf(s[nt][2], s[nt][3]);
      unsigned int* pr = reinterpret_cast<unsigned int*>(
          pq + lr * PQ_STR + nt * 16 + lg * 4);
      pr[0] = w0;
      pr[1] = w1;
    }

    // ---- PV: O = P @ V (K=224; slice 6 out-of-range parts = zero regs) ----
    f32x4 o[4];
#pragma unroll
    for (int nt = 0; nt < 4; ++nt) o[nt] = (f32x4){0.f, 0.f, 0.f, 0.f};
    const ushort4 zz = {0, 0, 0, 0};
#pragma unroll
    for (int ks = 0; ks < 7; ++ks) {
      union __align__(16) { struct { ushort4 lo, hi; } u; bf16x8 v; } pa;
      if (ks < 6 || lg < 2) {
        const char* pap = reinterpret_cast<const char*>(pq) + lr * (PQ_STR * 2) + ks * 64 + lg * 16;
        pa.u.lo = *reinterpret_cast<const ushort4*>(pap);
        pa.u.hi = *reinterpret_cast<const ushort4*>(pap + 8);
      } else {
        pa.u.lo = zz; pa.u.hi = zz;
      }
#pragma unroll
      for (int nt = 0; nt < 4; ++nt) {
        union __align__(16) { struct { ushort4 lo, hi; } u; bf16x8 v; } vb;
        if (ks < 6 || lg == 0) {
          const char* vbp = reinterpret_cast<const char*>(Vt) + (nt * 16 + lr) * 424 + ks * 64 + lg * 16;
          vb.u.lo = *reinterpret_cast<const ushort4*>(vbp);
          vb.u.hi = *reinterpret_cast<const ushort4*>(vbp + 8);
        } else {
          vb.u.lo = zz; vb.u.hi = zz;
        }
        o[nt] = MFMA_BF16(pa.v, vb.v, o[nt], 0, 0, 0);
      }
    }

    // ---- normalize + store valid rows ----
#pragma unroll
    for (int nt = 0; nt < 4; ++nt)
#pragma unroll
      for (int e = 0; e < 4; ++e) {
        int i = i0 + lg * 4 + e;
        if (i < lim) {
          Ob[(rowbase + i) * DIM + h * DH + nt * 16 + lr] = f2bf(o[nt][e] * rs[e]);
        }
      }
  }
}

// ---------------------------------------------------------------------------
extern "C" void kernel_launch(void* const* d_in, const int* in_sizes, int n_in,
                              void* d_out, int out_size, void* d_ws, size_t ws_size,
                              hipStream_t stream) {
  const float* x   = (const float*)d_in[0];
  const float* wq  = (const float*)d_in[1];
  const float* wkv = (const float*)d_in[2];
  const float* wo  = (const float*)d_in[3];
  const float* wb  = (const float*)d_in[4];
  const float* tbl = (const float*)d_in[5];
  float* out = (float*)d_out;

  const size_t elems = (size_t)BS * NP * DIM;
  unsigned short* Qb = (unsigned short*)d_ws;
  unsigned short* Kb = Qb + elems;
  unsigned short* Vb = Kb + elems;
  unsigned short* Ob = Qb;                       // attn output aliases Q dense rows
  unsigned short* Tb = Kb + (size_t)SEQ * DIM;   // table window in Kb pads (b=0)
  unsigned short* xb = (unsigned short*)d_out;   // bf16 x in d_out scratch

  hipFuncSetAttribute(reinterpret_cast<const void*>(attn_mfma),
                      hipFuncAttributeMaxDynamicSharedMemorySize, ATTN_LDS_B);

  const float qscale = 0.125f * 1.44269504088896f;   // 1/sqrt(64) * log2(e)
  dim3 blk(256);
  prep_table<<<dim3(26), blk, 0, stream>>>(tbl, Tb);
  wtrans<<<dim3(8, 8),  blk, 0, stream>>>(wq,  512,  0,   qscale, Qb);
  wtrans<<<dim3(16, 8), blk, 0, stream>>>(wkv, 1024, 512, 1.0f,   Qb);
  wtrans<<<dim3(8, 8),  blk, 0, stream>>>(wo,  512,  0,   1.0f,   Vb);
  cast_x<<<dim3(2048), blk, 0, stream>>>(x, xb);
  gemm_qkv<<<dim3(5856), blk, 0, stream>>>(xb, Qb, Qb, Kb, Vb);
  attn_mfma<<<dim3(BS * NB * NHEAD), blk, ATTN_LDS_B, stream>>>(Qb, Kb, Vb, Tb, Ob);
  gemm_out<<<dim3(1952), blk, 0, stream>>>(Ob, Vb, wb, out);
}

// Round 10
// 501.836 us; speedup vs baseline: 1.0121x; 1.0121x over previous
//
#include <hip/hip_runtime.h>
#include <hip/hip_bf16.h>
#include <cstdint>
#include <cstddef>

#define BS 16
#define SEQ 3900
#define DIM 512
#define NHEAD 8
#define DH 64
#define CHUNK 200
#define NB 20
#define NR 100
#define NP 4000
#define MAXPOS 512
#define MD 62400              // dense rows = BS*SEQ

typedef __attribute__((ext_vector_type(8))) short bf16x8;
typedef __attribute__((ext_vector_type(8))) unsigned short u16x8;
typedef __attribute__((ext_vector_type(4))) float f32x4;
#define MFMA_BF16 __builtin_amdgcn_mfma_f32_16x16x32_bf16

// bf16 helpers
static __device__ __forceinline__ float bf2f(unsigned short u) {
  union { unsigned int i; float f; } v; v.i = ((unsigned int)u) << 16; return v.f;
}
static __device__ __forceinline__ unsigned short f2bf(float f) {   // RNE
  unsigned int x = __float_as_uint(f);
  unsigned int lsb = (x >> 16) & 1u;
  x += 0x7fffu + lsb;
  return (unsigned short)(x >> 16);
}

// global -> LDS direct copy, 16B per lane
static __device__ __forceinline__ void gload16(const void* g, void* l) {
  auto gp = reinterpret_cast<const __attribute__((address_space(1))) unsigned int*>(
      reinterpret_cast<uintptr_t>(g));
  auto lp = reinterpret_cast<__attribute__((address_space(3))) unsigned int*>(
      reinterpret_cast<uintptr_t>(l));
  __builtin_amdgcn_global_load_lds(gp, lp, 16, 0, 0);
}

// Pad-chunk addressing: row n of a [n][512] bf16 matrix stored in the pad rows
// (t=3900..3999) of a [16][4000][512] workspace buffer.  100 rows per chunk.
static __device__ __forceinline__ const unsigned short* wt_row(
    const unsigned short* base, int n) {
  unsigned ch = (unsigned)n / 100u;
  unsigned rr = (unsigned)n - ch * 100u;
  return base + (size_t)ch * (NP * DIM) + (size_t)SEQ * DIM + (size_t)rr * DIM;
}

// ---------------------------------------------------------------------------
// Kernel 0a: cast rel-pos table window (rows 305..720) to bf16 -> Kb pads(b0).
// ---------------------------------------------------------------------------
__global__ __launch_bounds__(256) void prep_table(
    const float* __restrict__ table, unsigned short* __restrict__ Tb)
{
  int idx = (blockIdx.x * 256 + threadIdx.x) * 4;
  if (idx < 416 * 64) {
    float4 f = *reinterpret_cast<const float4*>(table + (size_t)305 * 64 + idx);
    ushort4 o;
    o.x = f2bf(f.x); o.y = f2bf(f.y); o.z = f2bf(f.z); o.w = f2bf(f.w);
    *reinterpret_cast<ushort4*>(Tb + idx) = o;
  }
}

// ---------------------------------------------------------------------------
// Kernel 0b: transpose+cast W[k][n] fp32 -> scale*Wt[n][k] bf16 into pad rows.
// wq gets scale = 0.125*log2(e): attention then uses exp2 directly (and Qtab,
// computed from the pre-scaled Q, inherits the scale).
// ---------------------------------------------------------------------------
__global__ __launch_bounds__(256) void wtrans(
    const float* __restrict__ W, int ldn, int n_off, float scale,
    unsigned short* __restrict__ base)
{
  __shared__ float ts[64][65];
  const int tid = threadIdx.x;
  const int n0 = blockIdx.x * 64;
  const int k0 = blockIdx.y * 64;
  {
    int kl = tid >> 4;
    int nl = (tid & 15) * 4;
#pragma unroll
    for (int p = 0; p < 4; ++p) {
      float4 f = *reinterpret_cast<const float4*>(
          W + (size_t)(k0 + kl + p * 16) * ldn + n0 + nl);
      ts[kl + p * 16][nl + 0] = f.x;
      ts[kl + p * 16][nl + 1] = f.y;
      ts[kl + p * 16][nl + 2] = f.z;
      ts[kl + p * 16][nl + 3] = f.w;
    }
  }
  __syncthreads();
  {
    int nl = tid >> 2;
    int kof = (tid & 3) * 16;
    int n = n0 + nl + n_off;
    unsigned ch = (unsigned)n / 100u;
    unsigned rr = (unsigned)n - ch * 100u;
    unsigned short* dst = base + (size_t)ch * (NP * DIM) + (size_t)SEQ * DIM
                          + (size_t)rr * DIM + k0 + kof;
    u16x8 o0, o1;
#pragma unroll
    for (int i = 0; i < 8; ++i) o0[i] = f2bf(ts[kof + i][nl] * scale);
#pragma unroll
    for (int i = 0; i < 8; ++i) o1[i] = f2bf(ts[kof + 8 + i][nl] * scale);
    *reinterpret_cast<u16x8*>(dst) = o0;
    *reinterpret_cast<u16x8*>(dst + 8) = o1;
  }
}

// ---------------------------------------------------------------------------
// Kernel 0c: cast x fp32 -> dense bf16 xb (stored in d_out scratch).
// ---------------------------------------------------------------------------
__global__ __launch_bounds__(256) void cast_x(
    const float* __restrict__ x, unsigned short* __restrict__ xb)
{
  const size_t total = (size_t)MD * DIM;
  size_t i = ((size_t)blockIdx.x * 256 + threadIdx.x) * 8;
  const size_t stride = (size_t)gridDim.x * 256 * 8;
  for (; i < total; i += stride) {
    float4 f0 = *reinterpret_cast<const float4*>(x + i);
    float4 f1 = *reinterpret_cast<const float4*>(x + i + 4);
    u16x8 o;
    o[0] = f2bf(f0.x); o[1] = f2bf(f0.y); o[2] = f2bf(f0.z); o[3] = f2bf(f0.w);
    o[4] = f2bf(f1.x); o[5] = f2bf(f1.y); o[6] = f2bf(f1.z); o[7] = f2bf(f1.w);
    *reinterpret_cast<u16x8*>(xb + i) = o;
  }
}

// ---------------------------------------------------------------------------
// Kernel 1: QKV projection, pure-bf16 MFMA with global_load_lds staging.
// NEW epilogue: C staged in LDS (XOR-swizzled, conflict-free) -> 8 coalesced
// 16B stores/thread instead of 64 scalar u16 stores + 16 row-divisions.
// ---------------------------------------------------------------------------
__global__ __launch_bounds__(256) void gemm_qkv(
    const unsigned short* __restrict__ xb, const unsigned short* __restrict__ WtBase,
    unsigned short* __restrict__ Qb, unsigned short* __restrict__ Kb,
    unsigned short* __restrict__ Vb)
{
  __shared__ unsigned short LDS[4][8 * 512];   // A: [0..1], B: [2..3]; C reuse: all

  int bid = blockIdx.x;                       // 5856 = 8 * 732
  bid = (bid & 7) * 732 + (bid >> 3);
  const int bm = bid / 12, bn = bid % 12;
  const int m0 = bm * 128, n0 = bn * 128;
  const int tid = threadIdx.x;
  const int wv = tid >> 6, ln = tid & 63;
  const int wr = wv >> 1, wc = wv & 1;
  const int lr = ln & 15, lg = ln >> 4;

  const int sl = ln & 15, sk = (ln >> 4) * 8;
  const int q0 = wv * 2, q1 = q0 + 1;
  int ar0 = m0 + (q0 >> 2) * 64 + (q0 & 3) * 16 + sl; if (ar0 >= MD) ar0 = MD - 1;
  int ar1 = m0 + (q1 >> 2) * 64 + (q1 & 3) * 16 + sl; if (ar1 >= MD) ar1 = MD - 1;
  const unsigned short* aS0 = xb + (size_t)ar0 * DIM + sk;
  const unsigned short* aS1 = xb + (size_t)ar1 * DIM + sk;
  const unsigned short* bS0 = wt_row(WtBase, n0 + (q0 >> 2) * 64 + (q0 & 3) * 16 + sl) + sk;
  const unsigned short* bS1 = wt_row(WtBase, n0 + (q1 >> 2) * 64 + (q1 & 3) * 16 + sl) + sk;

  f32x4 acc[4][4];
#pragma unroll
  for (int i = 0; i < 4; ++i)
#pragma unroll
    for (int j = 0; j < 4; ++j) acc[i][j] = (f32x4){0.f, 0.f, 0.f, 0.f};

#define STG_QKV(buf, koff)                            \
  gload16(aS0 + (koff), &LDS[buf][q0 * 512]);         \
  gload16(aS1 + (koff), &LDS[buf][q1 * 512]);         \
  gload16(bS0 + (koff), &LDS[2 + buf][q0 * 512]);     \
  gload16(bS1 + (koff), &LDS[2 + buf][q1 * 512]);

  STG_QKV(0, 0)
  __syncthreads();

  int p = 0;
  for (int s = 0; s < 16; ++s) {
    if (s < 15) { STG_QKV(p ^ 1, (s + 1) * 32) }
    const unsigned short* asp = LDS[p];
    const unsigned short* bsp = LDS[2 + p];
    bf16x8 af[4], bfr[4];
#pragma unroll
    for (int mt = 0; mt < 4; ++mt)
      af[mt] = *reinterpret_cast<const bf16x8*>(asp + (wr * 4 + mt) * 512 + ln * 8);
#pragma unroll
    for (int nt = 0; nt < 4; ++nt)
      bfr[nt] = *reinterpret_cast<const bf16x8*>(bsp + (wc * 4 + nt) * 512 + ln * 8);
#pragma unroll
    for (int mt = 0; mt < 4; ++mt)
#pragma unroll
      for (int nt = 0; nt < 4; ++nt)
        acc[mt][nt] = MFMA_BF16(af[mt], bfr[nt], acc[mt][nt], 0, 0, 0);
    __syncthreads();
    p ^= 1;
  }

  // ---- epilogue: C -> LDS (swizzled) -> coalesced global stores ----
  unsigned short* dst; int nbase;
  if (n0 < 512)       { dst = Qb; nbase = 0; }
  else if (n0 < 1024) { dst = Kb; nbase = 512; }
  else                { dst = Vb; nbase = 1024; }
  const int dcol0 = n0 - nbase;

  unsigned char* Cb8 = reinterpret_cast<unsigned char*>(&LDS[0][0]);  // [128][256B]
#pragma unroll
  for (int mt = 0; mt < 4; ++mt) {
#pragma unroll
    for (int e = 0; e < 4; ++e) {
      int r = wr * 64 + mt * 16 + lg * 4 + e;       // (r>>2)&3 == lg
#pragma unroll
      for (int nt = 0; nt < 4; ++nt) {
        int c2 = (wc * 128 + nt * 32 + lr * 2) ^ (lg << 5);
        *reinterpret_cast<unsigned short*>(Cb8 + r * 256 + c2) = f2bf(acc[mt][nt][e]);
      }
    }
  }
  __syncthreads();
  {
    const int g = tid >> 4, l16 = tid & 15;
#pragma unroll
    for (int i = 0; i < 8; ++i) {
      int r = g * 8 + i;
      int off = (l16 * 16) ^ (((r >> 2) & 3) << 5);
      uint4 v = *reinterpret_cast<const uint4*>(Cb8 + r * 256 + off);
      unsigned rd = m0 + r;
      if (rd < MD) {
        unsigned bb = rd / 3900u;
        unsigned tt = rd - bb * 3900u;
        *reinterpret_cast<uint4*>(dst + ((size_t)bb * NP + tt) * DIM + dcol0 + l16 * 8) = v;
      }
    }
  }
}

// ---------------------------------------------------------------------------
// Kernel 3: output projection; fp32 output + bias.  Epilogue: two 64-row
// half-passes through LDS (lg<<6 swizzle), bias folded into read-back.
// ---------------------------------------------------------------------------
__global__ __launch_bounds__(256) void gemm_out(
    const unsigned short* __restrict__ Ob, const unsigned short* __restrict__ WoBase,
    const float* __restrict__ bias, float* __restrict__ out)
{
  __shared__ unsigned short LDS[4][8 * 512];

  int bid = blockIdx.x;                       // 1952 = 8 * 244
  bid = (bid & 7) * 244 + (bid >> 3);
  const int bm = bid / 4, bn = bid % 4;
  const int m0 = bm * 128, n0 = bn * 128;
  const int tid = threadIdx.x;
  const int wv = tid >> 6, ln = tid & 63;
  const int wr = wv >> 1, wc = wv & 1;
  const int lr = ln & 15, lg = ln >> 4;

  const int sl = ln & 15, sk = (ln >> 4) * 8;
  const int q0 = wv * 2, q1 = q0 + 1;
  unsigned ar0 = m0 + (q0 >> 2) * 64 + (q0 & 3) * 16 + sl; if (ar0 >= MD) ar0 = MD - 1;
  unsigned ar1 = m0 + (q1 >> 2) * 64 + (q1 & 3) * 16 + sl; if (ar1 >= MD) ar1 = MD - 1;
  unsigned b0b = ar0 / 3900u, t0 = ar0 - b0b * 3900u;
  unsigned b1b = ar1 / 3900u, t1 = ar1 - b1b * 3900u;
  const unsigned short* aS0 = Ob + ((size_t)b0b * NP + t0) * DIM + sk;
  const unsigned short* aS1 = Ob + ((size_t)b1b * NP + t1) * DIM + sk;
  const unsigned short* bS0 = wt_row(WoBase, n0 + (q0 >> 2) * 64 + (q0 & 3) * 16 + sl) + sk;
  const unsigned short* bS1 = wt_row(WoBase, n0 + (q1 >> 2) * 64 + (q1 & 3) * 16 + sl) + sk;

  f32x4 acc[4][4];
#pragma unroll
  for (int i = 0; i < 4; ++i)
#pragma unroll
    for (int j = 0; j < 4; ++j) acc[i][j] = (f32x4){0.f, 0.f, 0.f, 0.f};

#define STG_OUT(buf, koff)                            \
  gload16(aS0 + (koff), &LDS[buf][q0 * 512]);         \
  gload16(aS1 + (koff), &LDS[buf][q1 * 512]);         \
  gload16(bS0 + (koff), &LDS[2 + buf][q0 * 512]);     \
  gload16(bS1 + (koff), &LDS[2 + buf][q1 * 512]);

  STG_OUT(0, 0)
  __syncthreads();

  int p = 0;
  for (int s = 0; s < 16; ++s) {
    if (s < 15) { STG_OUT(p ^ 1, (s + 1) * 32) }
    const unsigned short* asp = LDS[p];
    const unsigned short* bsp = LDS[2 + p];
    bf16x8 af[4], bfr[4];
#pragma unroll
    for (int mt = 0; mt < 4; ++mt)
      af[mt] = *reinterpret_cast<const bf16x8*>(asp + (wr * 4 + mt) * 512 + ln * 8);
#pragma unroll
    for (int nt = 0; nt < 4; ++nt)
      bfr[nt] = *reinterpret_cast<const bf16x8*>(bsp + (wc * 4 + nt) * 512 + ln * 8);
#pragma unroll
    for (int mt = 0; mt < 4; ++mt)
#pragma unroll
      for (int nt = 0; nt < 4; ++nt)
        acc[mt][nt] = MFMA_BF16(af[mt], bfr[nt], acc[mt][nt], 0, 0, 0);
    __syncthreads();
    p ^= 1;
  }

  // ---- epilogue: two half-passes (64 rows fp32 = 32KB) through LDS ----
  char* Cf = reinterpret_cast<char*>(&LDS[0][0]);     // [64][512B]
  const int gg = tid >> 5, l32 = tid & 31;
#pragma unroll
  for (int pass = 0; pass < 2; ++pass) {
    if (wr == pass) {
#pragma unroll
      for (int mt = 0; mt < 4; ++mt)
#pragma unroll
        for (int e = 0; e < 4; ++e) {
          int rl = mt * 16 + lg * 4 + e;            // (rl>>2)&3 == lg
#pragma unroll
          for (int nt = 0; nt < 4; ++nt) {
            int c4 = (wc * 256 + nt * 64 + lr * 4) ^ (lg << 6);
            *reinterpret_cast<float*>(Cf + rl * 512 + c4) = acc[mt][nt][e];
          }
        }
    }
    __syncthreads();
#pragma unroll
    for (int i = 0; i < 8; ++i) {
      int rl = gg * 8 + i;
      int off = (l32 * 16) ^ (((rl >> 2) & 3) << 6);
      float4 v = *reinterpret_cast<const float4*>(Cf + rl * 512 + off);
      int c = l32 * 4;
      float4 bv4 = *reinterpret_cast<const float4*>(bias + n0 + c);
      v.x += bv4.x; v.y += bv4.y; v.z += bv4.z; v.w += bv4.w;
      unsigned rd = m0 + pass * 64 + rl;
      if (rd < MD)
        *reinterpret_cast<float4*>(out + (size_t)rd * DIM + n0 + c) = v;
    }
    if (pass == 0) __syncthreads();
  }
}

// ---------------------------------------------------------------------------
// Kernel 2: MFMA attention (round-7 proven body, ~209us).
// Q pre-scaled by 0.125*log2e -> p = exp2f(qk + pos), no max-subtract; rcp.
// ---------------------------------------------------------------------------
#define KS_U16 12800
#define VT_U16 13568
#define PQ_STR 228
#define PQ_U16 (16*PQ_STR)
#define ATTN_LDS_B ((KS_U16 + VT_U16 + 4*PQ_U16) * 2)   // 81920

__global__ __launch_bounds__(256) void attn_mfma(
    const unsigned short* __restrict__ Qb, const unsigned short* __restrict__ Kb,
    const unsigned short* __restrict__ Vb, const unsigned short* __restrict__ Tb,
    unsigned short* __restrict__ Ob)
{
  extern __shared__ unsigned short smem[];
  unsigned short* Ks = smem;
  unsigned short* Vt = smem + KS_U16;

  const int tid = threadIdx.x;
  const int bid = blockIdx.x;
  const int h  = bid & 7;
  const int bm = bid >> 3;
  const int m  = bm % NB;
  const int b  = bm / NB;
  const size_t rowbase = (size_t)b * NP + (size_t)m * CHUNK;
  const int lim = (m == NB - 1) ? NR : CHUNK;

  for (int c = tid; c < CHUNK * 8; c += 256) {
    int j = c >> 3, k0 = (c & 7) * 8;
    uint4 kv = *reinterpret_cast<const uint4*>(Kb + (rowbase + j) * DIM + h * DH + k0);
    int byte = (j * 128 + k0 * 2) ^ ((j & 7) << 4);
    *reinterpret_cast<uint4*>(reinterpret_cast<char*>(Ks) + byte) = kv;
    uint4 vv4 = *reinterpret_cast<const uint4*>(Vb + (rowbase + j) * DIM + h * DH + k0);
    const unsigned short* vs = reinterpret_cast<const unsigned short*>(&vv4);
#pragma unroll
    for (int e = 0; e < 8; ++e)
      Vt[(k0 + e) * 212 + j] = vs[e];
  }
  __syncthreads();

  const int wv = tid >> 6, ln = tid & 63;
  const int lr = ln & 15, lg = ln >> 4;
  unsigned short* pq = smem + KS_U16 + VT_U16 + wv * PQ_U16;

  const int nMt = (lim + 15) >> 4;
  for (int mt = wv; mt < nMt; mt += 4) {
    const int i0 = mt << 4;

    const unsigned short* qp = Qb + (rowbase + i0 + lr) * DIM + h * DH + lg * 8;
    bf16x8 qa0 = *reinterpret_cast<const bf16x8*>(qp);
    bf16x8 qa1 = *reinterpret_cast<const bf16x8*>(qp + 32);

    // ---- Qtab = Qs @ T^T (pre-scaled; row-major per-wave buffer) ----
#pragma unroll
    for (int ct = 0; ct < 14; ++ct) {
      const unsigned short* tp = Tb + (size_t)(i0 + ct * 16 + lr) * 64 + lg * 8;
      bf16x8 tb0 = *reinterpret_cast<const bf16x8*>(tp);
      bf16x8 tb1 = *reinterpret_cast<const bf16x8*>(tp + 32);
      f32x4 acc = {0.f, 0.f, 0.f, 0.f};
      acc = MFMA_BF16(qa0, tb0, acc, 0, 0, 0);
      acc = MFMA_BF16(qa1, tb1, acc, 0, 0, 0);
#pragma unroll
      for (int e = 0; e < 4; ++e)
        pq[(lg * 4 + e) * PQ_STR + ct * 16 + lr] = f2bf(acc[e]);
    }

    // ---- QK^T (Q pre-scaled) ----
    f32x4 s[13];
#pragma unroll
    for (int nt = 0; nt < 13; ++nt) {
      int row = nt * 16 + lr;
      int b0 = (row * 128 + lg * 16) ^ ((row & 7) << 4);
      int b1 = (row * 128 + 64 + lg * 16) ^ ((row & 7) << 4);
      bf16x8 k0 = *reinterpret_cast<const bf16x8*>(reinterpret_cast<char*>(Ks) + b0);
      bf16x8 k1 = *reinterpret_cast<const bf16x8*>(reinterpret_cast<char*>(Ks) + b1);
      f32x4 acc = {0.f, 0.f, 0.f, 0.f};
      acc = MFMA_BF16(qa0, k0, acc, 0, 0, 0);
      acc = MFMA_BF16(qa1, k1, acc, 0, 0, 0);
      s[nt] = acc;
    }

    // ---- gather pos, p = exp2(qk+pos), accumulate sum (no max-sub) ----
    float sv[4] = {0.f, 0.f, 0.f, 0.f};
#pragma unroll
    for (int nt = 0; nt < 13; ++nt) {
      int j = nt * 16 + lr;
#pragma unroll
      for (int e = 0; e < 4; ++e) {
        int r = lg * 4 + e;
        float pos = bf2f(pq[r * PQ_STR + (r - j + 207)]);
        float t = s[nt][e] + pos;
        float p = (j < lim) ? exp2f(t) : 0.f;
        s[nt][e] = p;
        sv[e] += p;
      }
    }
#pragma unroll
    for (int e = 0; e < 4; ++e) {
      float x = sv[e];
      x += __shfl_xor(x, 1);
      x += __shfl_xor(x, 2);
      x += __shfl_xor(x, 4);
      x += __shfl_xor(x, 8);
      sv[e] = __builtin_amdgcn_rcpf(x);
    }

    // ---- write P (row-major, cols 0..207; Qtab already consumed) ----
#pragma unroll
    for (int nt = 0; nt < 13; ++nt)
#pragma unroll
      for (int e = 0; e < 4; ++e)
        pq[(lg * 4 + e) * PQ_STR + nt * 16 + lr] = f2bf(s[nt][e]);

    // ---- PV: O = P @ V (K=224; slice 6 out-of-range parts = zero regs) ----
    f32x4 o[4];
#pragma unroll
    for (int nt = 0; nt < 4; ++nt) o[nt] = (f32x4){0.f, 0.f, 0.f, 0.f};
    const ushort4 zz = {0, 0, 0, 0};
#pragma unroll
    for (int ks = 0; ks < 7; ++ks) {
      union __align__(16) { struct { ushort4 lo, hi; } u; bf16x8 v; } pa;
      if (ks < 6 || lg < 2) {
        const char* pap = reinterpret_cast<const char*>(pq) + lr * (PQ_STR * 2) + ks * 64 + lg * 16;
        pa.u.lo = *reinterpret_cast<const ushort4*>(pap);
        pa.u.hi = *reinterpret_cast<const ushort4*>(pap + 8);
      } else {
        pa.u.lo = zz; pa.u.hi = zz;
      }
#pragma unroll
      for (int nt = 0; nt < 4; ++nt) {
        union __align__(16) { struct { ushort4 lo, hi; } u; bf16x8 v; } vb;
        if (ks < 6 || lg == 0) {
          const char* vbp = reinterpret_cast<const char*>(Vt) + (nt * 16 + lr) * 424 + ks * 64 + lg * 16;
          vb.u.lo = *reinterpret_cast<const ushort4*>(vbp);
          vb.u.hi = *reinterpret_cast<const ushort4*>(vbp + 8);
        } else {
          vb.u.lo = zz; vb.u.hi = zz;
        }
        o[nt] = MFMA_BF16(pa.v, vb.v, o[nt], 0, 0, 0);
      }
    }

    // ---- normalize (mul by rcp) + store valid rows ----
#pragma unroll
    for (int nt = 0; nt < 4; ++nt)
#pragma unroll
      for (int e = 0; e < 4; ++e) {
        int i = i0 + lg * 4 + e;
        if (i < lim) {
          Ob[(rowbase + i) * DIM + h * DH + nt * 16 + lr] = f2bf(o[nt][e] * sv[e]);
        }
      }
  }
}

// ---------------------------------------------------------------------------
extern "C" void kernel_launch(void* const* d_in, const int* in_sizes, int n_in,
                              void* d_out, int out_size, void* d_ws, size_t ws_size,
                              hipStream_t stream) {
  const float* x   = (const float*)d_in[0];
  const float* wq  = (const float*)d_in[1];
  const float* wkv = (const float*)d_in[2];
  const float* wo  = (const float*)d_in[3];
  const float* wb  = (const float*)d_in[4];
  const float* tbl = (const float*)d_in[5];
  float* out = (float*)d_out;

  const size_t elems = (size_t)BS * NP * DIM;
  unsigned short* Qb = (unsigned short*)d_ws;
  unsigned short* Kb = Qb + elems;
  unsigned short* Vb = Kb + elems;
  unsigned short* Ob = Qb;                       // attn output aliases Q dense rows
  unsigned short* Tb = Kb + (size_t)SEQ * DIM;   // table window in Kb pads (b=0)
  unsigned short* xb = (unsigned short*)d_out;   // bf16 x in d_out scratch

  hipFuncSetAttribute(reinterpret_cast<const void*>(attn_mfma),
                      hipFuncAttributeMaxDynamicSharedMemorySize, ATTN_LDS_B);

  const float qscale = 0.125f * 1.44269504088896f;   // 1/sqrt(64) * log2(e)
  dim3 blk(256);
  prep_table<<<dim3(26), blk, 0, stream>>>(tbl, Tb);
  wtrans<<<dim3(8, 8),  blk, 0, stream>>>(wq,  512,  0,   qscale, Qb);
  wtrans<<<dim3(16, 8), blk, 0, stream>>>(wkv, 1024, 512, 1.0f,   Qb);
  wtrans<<<dim3(8, 8),  blk, 0, stream>>>(wo,  512,  0,   1.0f,   Vb);
  cast_x<<<dim3(2048), blk, 0, stream>>>(x, xb);
  gemm_qkv<<<dim3(5856), blk, 0, stream>>>(xb, Qb, Qb, Kb, Vb);
  attn_mfma<<<dim3(BS * NB * NHEAD), blk, ATTN_LDS_B, stream>>>(Qb, Kb, Vb, Tb, Ob);
  gemm_out<<<dim3(1952), blk, 0, stream>>>(Ob, Vb, wb, out);
}